// Round 7
// baseline (5107.064 us; speedup 1.0000x reference)
//
#include <hip/hip_runtime.h>
#include <math.h>

#define HH 384
#define WW 512
#define HW 196608            // 384*512
#define QHW 49152            // HW/4
#define CHW 983040           // 5*HW
#define FLOW_N 3145728       // 8*2*HW
#define NQUADS 393216        // 8*QHW
#define NBF 1536             // flow blocks (NQUADS/256); 192/XCD = one batch/XCD
#define NBI 1536             // img blocks, 4 px/thread: 1536*256*4 = 8*HW
#define OUT_FLOW_OFF 16
#define OUT_IMG_OFF (16 + FLOW_N)
#define EPS_F 1e-5f
#define EPS_S (1e-5f / 6400.0f)   // smooth-term eps in raw-x domain (S is deg-1 homog in 80x)
#define INV_HW (1.0f/196608.0f)

// single-instruction HW ops (~1 ulp); med3 == min(max(x,lo),hi) for finite x
__device__ __forceinline__ float rsq_f(float x)  { return __builtin_amdgcn_rsqf(x); }
__device__ __forceinline__ float ln_f(float x)   { return 0.69314718055994531f * __builtin_amdgcn_logf(x); }
__device__ __forceinline__ float sqrt_f(float x) { return __builtin_amdgcn_sqrtf(x); }
__device__ __forceinline__ float med3(float x, float lo, float hi) {
  return __builtin_amdgcn_fmed3f(x, lo, hi);
}

// ---- JAX threefry2x32 (bit-exact integer path), host+device ----
__host__ __device__ __forceinline__ void tf2x32(unsigned k0, unsigned k1,
                                                unsigned x0, unsigned x1,
                                                unsigned& o0, unsigned& o1) {
  const unsigned ks2 = k0 ^ k1 ^ 0x1BD11BDAu;
  x0 += k0; x1 += k1;
#define TFR(r) x0 += x1; x1 = (x1 << (r)) | (x1 >> (32 - (r))); x1 ^= x0;
  TFR(13) TFR(15) TFR(26) TFR(6)
  x0 += k1;  x1 += ks2 + 1u;
  TFR(17) TFR(29) TFR(16) TFR(24)
  x0 += ks2; x1 += k0 + 2u;
  TFR(13) TFR(15) TFR(26) TFR(6)
  x0 += k0;  x1 += k1 + 3u;
  TFR(17) TFR(29) TFR(16) TFR(24)
  x0 += k1;  x1 += ks2 + 4u;
  TFR(13) TFR(15) TFR(26) TFR(6)
  x0 += ks2; x1 += k0 + 5u;
#undef TFR
  o0 = x0; o1 = x1;
}

// bits -> NOISE_STD * sqrt(2) * erfinv(uniform(lo,1))   (JAX normal * 0.05)
__device__ __forceinline__ float noise_from_bits(unsigned bits) {
  const float LO = -0.99999994f;                    // nextafter(-1,0)
  float f = __uint_as_float((bits >> 9) | 0x3F800000u) - 1.0f;  // [0,1)
  float u = fmaxf(LO, f * 2.0f + LO);               // (hi-lo) rounds to 2.0f
  // -log1p(-u^2) via factored form (accurate near |u|~1) + HW log
  float w = -ln_f((1.0f - u) * (1.0f + u));
  float p;
  if (w < 5.0f) {
    w -= 2.5f;
    p = 2.81022636e-08f;
    p = p * w + 3.43273939e-07f;
    p = p * w + -3.5233877e-06f;
    p = p * w + -4.39150654e-06f;
    p = p * w + 0.00021858087f;
    p = p * w + -0.00125372503f;
    p = p * w + -0.00417768164f;
    p = p * w + 0.246640727f;
    p = p * w + 1.50140941f;
  } else {
    w = sqrt_f(w) - 3.0f;
    p = -0.000200214257f;
    p = p * w + 0.000100950558f;
    p = p * w + 0.00134934322f;
    p = p * w + -0.00367342844f;
    p = p * w + 0.00573950773f;
    p = p * w + -0.0076224613f;
    p = p * w + 0.00943887047f;
    p = p * w + 1.00167406f;
    p = p * w + 2.83297682f;
  }
  float z = 1.4142135623730951f * (p * u);
  return 0.05f * z;
}

__device__ __forceinline__ float upd(float x, float g) {
  g = med3(g, -0.03f, 0.03f);
  return med3(x - 10.0f * g, -1.0f, 1.0f);
}

// EXACT JAX partitionable-threefry bits: counter = (0, idx), output o0^o1.
__device__ __forceinline__ float noise_at(unsigned ka, unsigned kb, unsigned idx) {
  unsigned o0, o1;
  tf2x32(ka, kb, 0u, idx, o0, o1);
  return noise_from_bits(o0 ^ o1);
}

__device__ __forceinline__ float clip1(float x) { return med3(x, -1.0f, 1.0f); }

// add noise to 4 results and store as float4 (non-final path)
__device__ __forceinline__ void noise_store4(float* dst, const float* xn,
                                             unsigned ka, unsigned kb, unsigned idx0) {
  float r[4];
#pragma unroll
  for (int j = 0; j < 4; ++j)
    r[j] = clip1(xn[j] + noise_at(ka, kb, idx0 + (unsigned)j));
  *(float4*)dst = make_float4(r[0], r[1], r[2], r[3]);
}

// ---- kernels ----
__global__ void k_init(double* acc, float* sw, const float* lw) {
  int t = threadIdx.x;
  if (t < 32) acc[t] = 0.0;
  if (t == 32) {
    sw[0] = expf(lw[0]) * INV_HW * 0.5f;    // data-term scale
    sw[1] = expf(lw[1]) * INV_HW * 80.0f;   // smooth-term scale (incl d(flow)/dx = 80)
  }
}

// flow noise_0: compact (B,2,H,W) buffer, noise indexed in original 5-ch layout
__global__ __launch_bounds__(256) void k_fnoise0(const float* __restrict__ init,
    float* __restrict__ Y, unsigned ka, unsigned kb) {
  int e = blockIdx.x * 256 + threadIdx.x;    // [0, FLOW_N)
  int b = e / (2 * HW);
  int r = e - b * 2 * HW;
  int orig = b * CHW + r;                    // original element index (channels 0..1)
  Y[e] = clip1(init[orig] + noise_at(ka, kb, (unsigned)orig));
}

// ---- MERGED step kernel: flow grad step (blocks [0,NBF)) + ONE img step for
//      all img pixels (blocks [NBF, NBF+NBI)). Same stream/graph node ->
//      img VALU work fills the flow blocks' stall and drain slots.
//      Flow part == round-4 fstep4 (proven); img part == k_img body, one
//      iteration, state spilled to S (out's img region; dead until the end).
//      XCD-slab swizzle on both parts: batch b lives on XCD b for flow src,
//      dst, and img state alike. Bit-exact: identical per-element FP op order,
//      identical noise indices/keys; fp32 state round-trip is exact.
template <bool FINAL>
__global__ __launch_bounds__(256) void k_step(const float* __restrict__ X,
    float* __restrict__ Y, float* __restrict__ S,
    const float* __restrict__ init, const float* __restrict__ in2,
    const float* __restrict__ sw,
    unsigned fka, unsigned fkb,     // flow noise key  K[t+1] (unused if FINAL)
    unsigned ika, unsigned ikb,     // img  noise key  K[t]
    int first) {                    // img loads from init on step 0
  if (blockIdx.x < NBF) {
    // ================= flow part (verbatim round-4 fstep4) =================
    int wb = (blockIdx.x & 7) * (NBF / 8) + (blockIdx.x >> 3);
    int tid = wb * 256 + threadIdx.x;           // [0, NQUADS)
    int b = tid / QHW;
    int q = tid - b * QHW;
    int p = q * 4;                              // pixel base, multiple of 4
    int h = p >> 9, w = p & 511;
    float s1v = sw[1];
    const float* F0 = X + b * 2 * HW;
    const float* F1 = F0 + HW;
    const bool wpos = (w > 0), wend = (w == 508);
    const bool hpos = (h > 0), hlast = (h == 383);

    float cf[2][5], fm1[2], dw[2][4], dwm1[2], uf[2][5];
    {
      float4 a0 = *(const float4*)(F0 + p);
      float4 a1 = *(const float4*)(F1 + p);
      cf[0][0]=a0.x; cf[0][1]=a0.y; cf[0][2]=a0.z; cf[0][3]=a0.w;
      cf[1][0]=a1.x; cf[1][1]=a1.y; cf[1][2]=a1.z; cf[1][3]=a1.w;
      cf[0][4] = wend ? cf[0][3] : F0[p + 4];
      cf[1][4] = wend ? cf[1][3] : F1[p + 4];
      fm1[0] = wpos ? F0[p - 1] : cf[0][0];
      fm1[1] = wpos ? F1[p - 1] : cf[1][0];
      if (!hlast) {
        float4 d0 = *(const float4*)(F0 + p + WW);
        float4 d1 = *(const float4*)(F1 + p + WW);
        dw[0][0]=d0.x; dw[0][1]=d0.y; dw[0][2]=d0.z; dw[0][3]=d0.w;
        dw[1][0]=d1.x; dw[1][1]=d1.y; dw[1][2]=d1.z; dw[1][3]=d1.w;
        dwm1[0] = wpos ? F0[p + WW - 1] : fm1[0];
        dwm1[1] = wpos ? F1[p + WW - 1] : fm1[1];
      } else {
#pragma unroll
        for (int c = 0; c < 2; ++c) {
          for (int j = 0; j < 4; ++j) dw[c][j] = cf[c][j];   // dy = 0
          dwm1[c] = fm1[c];
        }
      }
      if (hpos) {
        float4 u0 = *(const float4*)(F0 + p - WW);
        float4 u1 = *(const float4*)(F1 + p - WW);
        uf[0][0]=u0.x; uf[0][1]=u0.y; uf[0][2]=u0.z; uf[0][3]=u0.w;
        uf[1][0]=u1.x; uf[1][1]=u1.y; uf[1][2]=u1.z; uf[1][3]=u1.w;
        uf[0][4] = wend ? uf[0][3] : F0[p - WW + 4];
        uf[1][4] = wend ? uf[1][3] : F1[p - WW + 4];
      } else {
#pragma unroll
        for (int c = 0; c < 2; ++c)
          for (int j = 0; j < 5; ++j) uf[c][j] = cf[c][j];   // masked by hpos
      }
    }

    float dxc[2][4], dyc[2][4], invSc[4], dxu[2][4], dyu[2][4], invSu[4];
    float dxl[2], dyl[2], invSL;
#pragma unroll
    for (int j = 0; j < 4; ++j) {
#pragma unroll
      for (int c = 0; c < 2; ++c) {
        dxc[c][j] = cf[c][j + 1] - cf[c][j];
        dyc[c][j] = dw[c][j] - cf[c][j];
        dxu[c][j] = uf[c][j + 1] - uf[c][j];
        dyu[c][j] = cf[c][j] - uf[c][j];
      }
      invSc[j] = rsq_f(dxc[0][j]*dxc[0][j] + dxc[1][j]*dxc[1][j]
                     + dyc[0][j]*dyc[0][j] + dyc[1][j]*dyc[1][j] + EPS_S);
      invSu[j] = rsq_f(dxu[0][j]*dxu[0][j] + dxu[1][j]*dxu[1][j]
                     + dyu[0][j]*dyu[0][j] + dyu[1][j]*dyu[1][j] + EPS_S);
    }
    dxl[0] = cf[0][0] - fm1[0];  dxl[1] = cf[1][0] - fm1[1];
    dyl[0] = dwm1[0] - fm1[0];   dyl[1] = dwm1[1] - fm1[1];
    invSL = rsq_f(dxl[0]*dxl[0] + dxl[1]*dxl[1]
                + dyl[0]*dyl[0] + dyl[1]*dyl[1] + EPS_S);

    float xnF[2][4];
#pragma unroll
    for (int j = 0; j < 4; ++j) {
#pragma unroll
      for (int c = 0; c < 2; ++c) {
        float g = -(dxc[c][j] + dyc[c][j]) * invSc[j];
        if (j == 0) { if (wpos) g += dxl[c] * invSL; }
        else        { g += dxc[c][j - 1] * invSc[j - 1]; }
        if (hpos)   { g += dyu[c][j] * invSu[j]; }
        xnF[c][j] = upd(cf[c][j], g * s1v);
      }
    }

    if (!FINAL) {
      int nbase = b * CHW + p;
      int sb = b * 2 * HW + p;
      noise_store4(Y + sb,      &xnF[0][0], fka, fkb, (unsigned)nbase);
      noise_store4(Y + sb + HW, &xnF[1][0], fka, fkb, (unsigned)(nbase + HW));
    } else {
      float* outF = Y + OUT_FLOW_OFF + b * 2 * HW;
      *(float4*)(outF + p)      = make_float4(xnF[0][0]*80.f, xnF[0][1]*80.f,
                                              xnF[0][2]*80.f, xnF[0][3]*80.f);
      *(float4*)(outF + HW + p) = make_float4(xnF[1][0]*80.f, xnF[1][1]*80.f,
                                              xnF[1][2]*80.f, xnF[1][3]*80.f);
    }
  } else {
    // ================= img part: one step for 4 px/thread =================
    int fb = (int)blockIdx.x - NBF;
    int wb = (fb & 7) * (NBI / 8) + (fb >> 3);
    int tid = wb * 256 + threadIdx.x;           // [0, NQUADS)
    int b = tid / QHW;
    int q = tid - b * QHW;
    int p = q * 4;
    float s0 = sw[0];
    float* Sp = S + b * 3 * HW + p;             // compact (B,3,H,W) state
    const float* I2 = in2 + b * 3 * HW + p;
    unsigned nb = (unsigned)(b * CHW + 2 * HW + p);   // ch-2 noise index

    float x[3][4], iv[3][4];
#pragma unroll
    for (int c = 0; c < 3; ++c) {
      float4 v = first ? *(const float4*)(init + b * CHW + 2 * HW + c * HW + p)
                       : *(const float4*)(Sp + c * HW);
      x[c][0]=v.x; x[c][1]=v.y; x[c][2]=v.z; x[c][3]=v.w;
      float4 wv = *(const float4*)(I2 + c * HW);
      iv[c][0] = ((wv.x * 2.0f - 1.0f) + 1.0f) * 0.5f;
      iv[c][1] = ((wv.y * 2.0f - 1.0f) + 1.0f) * 0.5f;
      iv[c][2] = ((wv.z * 2.0f - 1.0f) + 1.0f) * 0.5f;
      iv[c][3] = ((wv.w * 2.0f - 1.0f) + 1.0f) * 0.5f;
    }
#pragma unroll
    for (int j = 0; j < 4; ++j) {
      float y0 = clip1(x[0][j] + noise_at(ika, ikb, nb + (unsigned)j));
      float y1 = clip1(x[1][j] + noise_at(ika, ikb, nb + (unsigned)(HW + j)));
      float y2 = clip1(x[2][j] + noise_at(ika, ikb, nb + (unsigned)(2 * HW + j)));
      float d0 = (y0 + 1.0f) * 0.5f - iv[0][j];
      float d1 = (y1 + 1.0f) * 0.5f - iv[1][j];
      float d2 = (y2 + 1.0f) * 0.5f - iv[2][j];
      float A = d0*d0 + d1*d1 + d2*d2;
      float sI = s0 * rsq_f(A + EPS_F);
      x[0][j] = upd(y0, d0 * sI);
      x[1][j] = upd(y1, d1 * sI);
      x[2][j] = upd(y2, d2 * sI);
    }
#pragma unroll
    for (int c = 0; c < 3; ++c) {
      float4 v;
      if (!FINAL) v = make_float4(x[c][0], x[c][1], x[c][2], x[c][3]);
      else v = make_float4((x[c][0]+1.0f)*0.5f, (x[c][1]+1.0f)*0.5f,
                           (x[c][2]+1.0f)*0.5f, (x[c][3]+1.0f)*0.5f);
      *(float4*)(Sp + c * HW) = v;
    }
  }
}

__device__ __forceinline__ void block_acc2(double v0, double v1, double* a0, double* a1) {
  for (int off = 32; off > 0; off >>= 1) {
    v0 += __shfl_down(v0, off, 64);
    v1 += __shfl_down(v1, off, 64);
  }
  __shared__ double s0m[4], s1m[4];
  int lane = threadIdx.x & 63, wv = threadIdx.x >> 6;
  if (lane == 0) { s0m[wv] = v0; s1m[wv] = v1; }
  __syncthreads();
  if (threadIdx.x == 0) {
    atomicAdd(a0, s0m[0] + s0m[1] + s0m[2] + s0m[3]);
    atomicAdd(a1, s1m[0] + s1m[1] + s1m[2] + s1m[3]);
  }
}

// 96 blocks per batch, each covering 8 contiguous 256-px chunks
__global__ __launch_bounds__(256) void k_pos_energy(const float* __restrict__ t1,
    const float* __restrict__ in1, const float* __restrict__ in2,
    double* __restrict__ acc) {
  int blk = blockIdx.x;
  int b = blk / 96;
  int local = blk - b * 96;
  const float* T0 = t1 + b * 2 * HW;
  const float* T1 = T0 + HW;
  const float* I1 = in1 + b * 3 * HW;
  const float* I2 = in2 + b * 3 * HW;
  double data = 0.0, smooth = 0.0;
  for (int it = 0; it < 8; ++it) {
    int p = (local * 8 + it) * 256 + threadIdx.x;
    int h = p >> 9, w = p & 511;
    float f00 = (T0[p] / 80.0f) * 80.0f;     // mirror (t/80)*80 roundtrip
    float f10 = (T1[p] / 80.0f) * 80.0f;
    float dx0 = 0, dx1 = 0, dy0 = 0, dy1 = 0;
    if (w < 511) { dx0 = (T0[p+1]/80.0f)*80.0f - f00;  dx1 = (T1[p+1]/80.0f)*80.0f - f10; }
    if (h < 383) { dy0 = (T0[p+WW]/80.0f)*80.0f - f00; dy1 = (T1[p+WW]/80.0f)*80.0f - f10; }
    smooth += (double)sqrtf(dx0*dx0 + dx1*dx1 + dy0*dy0 + dy1*dy1 + EPS_F);
    float d0 = ((I1[p]*2.0f-1.0f)+1.0f)*0.5f        - ((I2[p]*2.0f-1.0f)+1.0f)*0.5f;
    float d1 = ((I1[p+HW]*2.0f-1.0f)+1.0f)*0.5f     - ((I2[p+HW]*2.0f-1.0f)+1.0f)*0.5f;
    float d2 = ((I1[p+2*HW]*2.0f-1.0f)+1.0f)*0.5f   - ((I2[p+2*HW]*2.0f-1.0f)+1.0f)*0.5f;
    data += (double)sqrtf(d0*d0 + d1*d1 + d2*d2 + EPS_F);
  }
  block_acc2(data, smooth, &acc[b], &acc[8 + b]);
}

__global__ __launch_bounds__(256) void k_neg_energy(const float* __restrict__ out,
    const float* __restrict__ in2, double* __restrict__ acc) {
  int blk = blockIdx.x;
  int b = blk / 96;
  int local = blk - b * 96;
  const float* F0 = out + OUT_FLOW_OFF + b * 2 * HW;   // already = 80*x
  const float* F1 = F0 + HW;
  const float* I = out + OUT_IMG_OFF + b * 3 * HW;     // already = (x+1)/2
  const float* I2 = in2 + b * 3 * HW;
  double data = 0.0, smooth = 0.0;
  for (int it = 0; it < 8; ++it) {
    int p = (local * 8 + it) * 256 + threadIdx.x;
    int h = p >> 9, w = p & 511;
    float f00 = F0[p], f10 = F1[p];
    float dx0 = 0, dx1 = 0, dy0 = 0, dy1 = 0;
    if (w < 511) { dx0 = F0[p + 1] - f00;  dx1 = F1[p + 1] - f10; }
    if (h < 383) { dy0 = F0[p + WW] - f00; dy1 = F1[p + WW] - f10; }
    smooth += (double)sqrtf(dx0*dx0 + dx1*dx1 + dy0*dy0 + dy1*dy1 + EPS_F);
    float d0 = I[p]        - ((I2[p]*2.0f-1.0f)+1.0f)*0.5f;
    float d1 = I[p+HW]     - ((I2[p+HW]*2.0f-1.0f)+1.0f)*0.5f;
    float d2 = I[p+2*HW]   - ((I2[p+2*HW]*2.0f-1.0f)+1.0f)*0.5f;
    data += (double)sqrtf(d0*d0 + d1*d1 + d2*d2 + EPS_F);
  }
  block_acc2(data, smooth, &acc[16 + b], &acc[24 + b]);
}

__global__ void k_finalize(const double* __restrict__ acc,
                           const float* __restrict__ lw, float* __restrict__ out) {
  int t = threadIdx.x;
  if (t < 16) {
    int b = t & 7, neg = t >> 3;
    double data   = acc[neg * 16 + b];
    double smooth = acc[neg * 16 + 8 + b];
    double e0 = exp((double)lw[0]), e1 = exp((double)lw[1]);
    out[t] = (float)((e0 * data + e1 * smooth) / 196608.0);
  }
}

extern "C" void kernel_launch(void* const* d_in, const int* in_sizes, int n_in,
                              void* d_out, int out_size, void* d_ws, size_t ws_size,
                              hipStream_t stream) {
  const float* t1  = (const float*)d_in[0];
  const float* in1 = (const float*)d_in[1];
  const float* in2 = (const float*)d_in[2];
  const float* init = (const float*)d_in[3];
  const float* lw  = (const float*)d_in[4];
  float* out = (float*)d_out;

  double* acc = (double*)d_ws;                          // 32 doubles
  float* sw = (float*)((char*)d_ws + 256);              // 2 floats
  float* bufFA = (float*)((char*)d_ws + 2048);          // flow ping (12.6 MB)
  size_t need = 2048 + 2 * (size_t)FLOW_N * sizeof(float);
  float* bufFB = (ws_size >= need) ? bufFA + FLOW_N
                                   : out + OUT_FLOW_OFF;  // fallback: d_out flow region
  float* imgS = out + OUT_IMG_OFF;                      // img state lives in out

  // host-side threefry split: keys[t] = tf(0,1,0,t)  (pure integer function)
  unsigned K0[200], K1[200];
  for (int t = 0; t < 200; ++t) tf2x32(0u, 1u, 0u, (unsigned)t, K0[t], K1[t]);

  k_init<<<1, 64, 0, stream>>>(acc, sw, lw);
  k_pos_energy<<<8 * 96, 256, 0, stream>>>(t1, in1, in2, acc);

  // ---- merged trajectory: fnoise0, then 199 merged {flow grad+noise, img
  //      step t}, then final merged {flow grad-only -> out, img step 199 ->
  //      out}. Flow parity: noise0 -> bufFB; t even FB->FA, t odd FA->FB;
  //      t=198 even -> FA; FINAL reads bufFA.
  k_fnoise0<<<FLOW_N / 256, 256, 0, stream>>>(init, bufFB, K0[0], K1[0]);
  for (int t = 0; t < 199; ++t) {
    const float* src = (t % 2 == 0) ? bufFB : bufFA;
    float* dst       = (t % 2 == 0) ? bufFA : bufFB;
    k_step<false><<<NBF + NBI, 256, 0, stream>>>(src, dst, imgS, init, in2, sw,
                                                 K0[t + 1], K1[t + 1],
                                                 K0[t], K1[t], t == 0);
  }
  k_step<true><<<NBF + NBI, 256, 0, stream>>>(bufFA, out, imgS, init, in2, sw,
                                              0u, 0u, K0[199], K1[199], 0);

  k_neg_energy<<<8 * 96, 256, 0, stream>>>(out, in2, acc);
  k_finalize<<<1, 64, 0, stream>>>(acc, lw, out);
}

// Round 8
// 4587.659 us; speedup vs baseline: 1.1132x; 1.1132x over previous
//
#include <hip/hip_runtime.h>
#include <math.h>

#define HH 384
#define WW 512
#define HW 196608            // 384*512
#define QHW 49152            // HW/4
#define CHW 983040           // 5*HW
#define FLOW_N 3145728       // 8*2*HW
#define NQUADS 393216        // 8*QHW
#define OUT_FLOW_OFF 16
#define OUT_IMG_OFF (16 + FLOW_N)
#define EPS_F 1e-5f
#define EPS_S (1e-5f / 6400.0f)   // smooth-term eps in raw-x domain (S is deg-1 homog in 80x)
#define INV_HW (1.0f/196608.0f)

// single-instruction HW ops (~1 ulp); med3 == min(max(x,lo),hi) for finite x
__device__ __forceinline__ float rsq_f(float x)  { return __builtin_amdgcn_rsqf(x); }
__device__ __forceinline__ float ln_f(float x)   { return 0.69314718055994531f * __builtin_amdgcn_logf(x); }
__device__ __forceinline__ float sqrt_f(float x) { return __builtin_amdgcn_sqrtf(x); }
__device__ __forceinline__ float med3(float x, float lo, float hi) {
  return __builtin_amdgcn_fmed3f(x, lo, hi);
}

// ---- JAX threefry2x32 (bit-exact integer path), host+device ----
__host__ __device__ __forceinline__ void tf2x32(unsigned k0, unsigned k1,
                                                unsigned x0, unsigned x1,
                                                unsigned& o0, unsigned& o1) {
  const unsigned ks2 = k0 ^ k1 ^ 0x1BD11BDAu;
  x0 += k0; x1 += k1;
#define TFR(r) x0 += x1; x1 = (x1 << (r)) | (x1 >> (32 - (r))); x1 ^= x0;
  TFR(13) TFR(15) TFR(26) TFR(6)
  x0 += k1;  x1 += ks2 + 1u;
  TFR(17) TFR(29) TFR(16) TFR(24)
  x0 += ks2; x1 += k0 + 2u;
  TFR(13) TFR(15) TFR(26) TFR(6)
  x0 += k0;  x1 += k1 + 3u;
  TFR(17) TFR(29) TFR(16) TFR(24)
  x0 += k1;  x1 += ks2 + 4u;
  TFR(13) TFR(15) TFR(26) TFR(6)
  x0 += ks2; x1 += k0 + 5u;
#undef TFR
  o0 = x0; o1 = x1;
}

// bits -> NOISE_STD * sqrt(2) * erfinv(uniform(lo,1))   (JAX normal * 0.05)
__device__ __forceinline__ float noise_from_bits(unsigned bits) {
  const float LO = -0.99999994f;                    // nextafter(-1,0)
  float f = __uint_as_float((bits >> 9) | 0x3F800000u) - 1.0f;  // [0,1)
  float u = fmaxf(LO, f * 2.0f + LO);               // (hi-lo) rounds to 2.0f
  // -log1p(-u^2) via factored form (accurate near |u|~1) + HW log
  float w = -ln_f((1.0f - u) * (1.0f + u));
  float p;
  if (w < 5.0f) {
    w -= 2.5f;
    p = 2.81022636e-08f;
    p = p * w + 3.43273939e-07f;
    p = p * w + -3.5233877e-06f;
    p = p * w + -4.39150654e-06f;
    p = p * w + 0.00021858087f;
    p = p * w + -0.00125372503f;
    p = p * w + -0.00417768164f;
    p = p * w + 0.246640727f;
    p = p * w + 1.50140941f;
  } else {
    w = sqrt_f(w) - 3.0f;
    p = -0.000200214257f;
    p = p * w + 0.000100950558f;
    p = p * w + 0.00134934322f;
    p = p * w + -0.00367342844f;
    p = p * w + 0.00573950773f;
    p = p * w + -0.0076224613f;
    p = p * w + 0.00943887047f;
    p = p * w + 1.00167406f;
    p = p * w + 2.83297682f;
  }
  float z = 1.4142135623730951f * (p * u);
  return 0.05f * z;
}

__device__ __forceinline__ float upd(float x, float g) {
  g = med3(g, -0.03f, 0.03f);
  return med3(x - 10.0f * g, -1.0f, 1.0f);
}

// EXACT JAX partitionable-threefry bits: counter = (0, idx), output o0^o1.
__device__ __forceinline__ float noise_at(unsigned ka, unsigned kb, unsigned idx) {
  unsigned o0, o1;
  tf2x32(ka, kb, 0u, idx, o0, o1);
  return noise_from_bits(o0 ^ o1);
}

__device__ __forceinline__ float clip1(float x) { return med3(x, -1.0f, 1.0f); }

// ---- kernels ----
__global__ void k_init(double* acc, float* sw, const float* lw) {
  int t = threadIdx.x;
  if (t < 32) acc[t] = 0.0;
  if (t == 32) {
    sw[0] = expf(lw[0]) * INV_HW * 0.5f;    // data-term scale
    sw[1] = expf(lw[1]) * INV_HW * 80.0f;   // smooth-term scale (incl d(flow)/dx = 80)
  }
}

// flow noise_0: compact (B,2,H,W) buffer, noise indexed in original 5-ch layout.
// XCD-slab swizzle so batch b is written by XCD b (matches fstep's slab map).
__global__ __launch_bounds__(256) void k_fnoise0(const float* __restrict__ init,
    float* __restrict__ Y, unsigned ka, unsigned kb) {
  int wb = (blockIdx.x & 7) * (FLOW_N / 256 / 8) + (blockIdx.x >> 3);
  int e = wb * 256 + threadIdx.x;            // [0, FLOW_N)
  int b = e / (2 * HW);
  int r = e - b * 2 * HW;
  int orig = b * CHW + r;                    // original element index (channels 0..1)
  Y[e] = clip1(init[orig] + noise_at(ka, kb, (unsigned)orig));
}

// flow grad step, 4 px/thread along w -> 1536 blocks = ONE residency round.
// XCD-slab swizzle: batch b lives on XCD b (ping-pong slab 3.1 MB < 4 MiB L2).
// THIS ROUND: noise chains (pure ALU, independent of the stencil) are computed
// BETWEEN load-issue and load-use -> ~2000 cy of threefry hides the L2 latency
// of the 13 stencil loads. Pure reorder of independent values: bit-exact.
template <bool FINAL>
__global__ __launch_bounds__(256) void k_fstep4(const float* __restrict__ X,
    float* __restrict__ Y, const float* __restrict__ sw,
    unsigned ka, unsigned kb) {
  int wb = (blockIdx.x & 7) * (NQUADS / 256 / 8) + (blockIdx.x >> 3);
  int tid = wb * 256 + threadIdx.x;           // [0, NQUADS)
  int b = tid / QHW;
  int q = tid - b * QHW;
  int p = q * 4;                              // pixel base, multiple of 4
  int h = p >> 9, w = p & 511;
  float s1v = sw[1];
  const float* F0 = X + b * 2 * HW;
  const float* F1 = F0 + HW;
  const bool wpos = (w > 0), wend = (w == 508);
  const bool hpos = (h > 0), hlast = (h == 383);

  // ---- stencil values; cf[c][4] duplicated at right edge so dx=0 ----
  float cf[2][5], fm1[2], dw[2][4], dwm1[2], uf[2][5];
  {
    float4 a0 = *(const float4*)(F0 + p);
    float4 a1 = *(const float4*)(F1 + p);
    cf[0][0]=a0.x; cf[0][1]=a0.y; cf[0][2]=a0.z; cf[0][3]=a0.w;
    cf[1][0]=a1.x; cf[1][1]=a1.y; cf[1][2]=a1.z; cf[1][3]=a1.w;
    cf[0][4] = wend ? cf[0][3] : F0[p + 4];
    cf[1][4] = wend ? cf[1][3] : F1[p + 4];
    fm1[0] = wpos ? F0[p - 1] : cf[0][0];
    fm1[1] = wpos ? F1[p - 1] : cf[1][0];
    if (!hlast) {
      float4 d0 = *(const float4*)(F0 + p + WW);
      float4 d1 = *(const float4*)(F1 + p + WW);
      dw[0][0]=d0.x; dw[0][1]=d0.y; dw[0][2]=d0.z; dw[0][3]=d0.w;
      dw[1][0]=d1.x; dw[1][1]=d1.y; dw[1][2]=d1.z; dw[1][3]=d1.w;
      dwm1[0] = wpos ? F0[p + WW - 1] : fm1[0];
      dwm1[1] = wpos ? F1[p + WW - 1] : fm1[1];
    } else {
#pragma unroll
      for (int c = 0; c < 2; ++c) {
        for (int j = 0; j < 4; ++j) dw[c][j] = cf[c][j];   // dy = 0
        dwm1[c] = fm1[c];
      }
    }
    if (hpos) {
      float4 u0 = *(const float4*)(F0 + p - WW);
      float4 u1 = *(const float4*)(F1 + p - WW);
      uf[0][0]=u0.x; uf[0][1]=u0.y; uf[0][2]=u0.z; uf[0][3]=u0.w;
      uf[1][0]=u1.x; uf[1][1]=u1.y; uf[1][2]=u1.z; uf[1][3]=u1.w;
      uf[0][4] = wend ? uf[0][3] : F0[p - WW + 4];
      uf[1][4] = wend ? uf[1][3] : F1[p - WW + 4];
    } else {
#pragma unroll
      for (int c = 0; c < 2; ++c)
        for (int j = 0; j < 5; ++j) uf[c][j] = cf[c][j];   // unused (masked by hpos)
    }
  }

  // ---- noise chains: independent of the loads above; runs while they land ----
  float nz[2][4];
  if (!FINAL) {
    int nbase = b * CHW + p;                 // noise index in original 5-ch layout
#pragma unroll
    for (int j = 0; j < 4; ++j)
      nz[0][j] = noise_at(ka, kb, (unsigned)(nbase + j));
#pragma unroll
    for (int j = 0; j < 4; ++j)
      nz[1][j] = noise_at(ka, kb, (unsigned)(nbase + HW + j));
  }

  // ---- shared S sites: SL = S(h,w-1); Sc[j] = S(h,w+j); Su[j] = S(h-1,w+j) ----
  float dxc[2][4], dyc[2][4], invSc[4], dxu[2][4], dyu[2][4], invSu[4];
  float dxl[2], dyl[2], invSL;
#pragma unroll
  for (int j = 0; j < 4; ++j) {
#pragma unroll
    for (int c = 0; c < 2; ++c) {
      dxc[c][j] = cf[c][j + 1] - cf[c][j];
      dyc[c][j] = dw[c][j] - cf[c][j];
      dxu[c][j] = uf[c][j + 1] - uf[c][j];
      dyu[c][j] = cf[c][j] - uf[c][j];
    }
    invSc[j] = rsq_f(dxc[0][j]*dxc[0][j] + dxc[1][j]*dxc[1][j]
                   + dyc[0][j]*dyc[0][j] + dyc[1][j]*dyc[1][j] + EPS_S);
    invSu[j] = rsq_f(dxu[0][j]*dxu[0][j] + dxu[1][j]*dxu[1][j]
                   + dyu[0][j]*dyu[0][j] + dyu[1][j]*dyu[1][j] + EPS_S);
  }
  dxl[0] = cf[0][0] - fm1[0];  dxl[1] = cf[1][0] - fm1[1];
  dyl[0] = dwm1[0] - fm1[0];   dyl[1] = dwm1[1] - fm1[1];
  invSL = rsq_f(dxl[0]*dxl[0] + dxl[1]*dxl[1]
              + dyl[0]*dyl[0] + dyl[1]*dyl[1] + EPS_S);

  // ---- grads + update ----
  float xnF[2][4];
#pragma unroll
  for (int j = 0; j < 4; ++j) {
#pragma unroll
    for (int c = 0; c < 2; ++c) {
      float g = -(dxc[c][j] + dyc[c][j]) * invSc[j];
      if (j == 0) { if (wpos) g += dxl[c] * invSL; }
      else        { g += dxc[c][j - 1] * invSc[j - 1]; }
      if (hpos)   { g += dyu[c][j] * invSu[j]; }
      xnF[c][j] = upd(cf[c][j], g * s1v);
    }
  }

  // ---- combine + store (or final transform) ----
  if (!FINAL) {
    int sb = b * 2 * HW + p;                 // compact store index
    float r0[4], r1[4];
#pragma unroll
    for (int j = 0; j < 4; ++j) {
      r0[j] = clip1(xnF[0][j] + nz[0][j]);   // same add, same order as before
      r1[j] = clip1(xnF[1][j] + nz[1][j]);
    }
    *(float4*)(Y + sb)      = make_float4(r0[0], r0[1], r0[2], r0[3]);
    *(float4*)(Y + sb + HW) = make_float4(r1[0], r1[1], r1[2], r1[3]);
  } else {
    float* outF = Y + OUT_FLOW_OFF + b * 2 * HW;
    *(float4*)(outF + p)      = make_float4(xnF[0][0]*80.f, xnF[0][1]*80.f,
                                            xnF[0][2]*80.f, xnF[0][3]*80.f);
    *(float4*)(outF + HW + p) = make_float4(xnF[1][0]*80.f, xnF[1][1]*80.f,
                                            xnF[1][2]*80.f, xnF[1][3]*80.f);
  }
}

// img channels: per-pixel independent 200-step recurrence, state in registers.
// ROUND-0 form (best measured: 2132 us across three attempted restructures).
__global__ __launch_bounds__(256, 8) void k_img(const float* __restrict__ init,
    const float* __restrict__ in2, const float* __restrict__ sw,
    float* __restrict__ out) {
  __shared__ unsigned Kl[404];
  int tid = threadIdx.x;
  if (tid < 202) {                            // split(key(1),200): tf(0,1,0,t); 2 pad
    unsigned a, bb;
    tf2x32(0u, 1u, 0u, (unsigned)tid, a, bb);
    Kl[2 * tid] = a; Kl[2 * tid + 1] = bb;
  }
  __syncthreads();
  int g = blockIdx.x * 256 + tid;             // [0, 8*HW)
  int b = g / HW;
  int p = g - b * HW;
  float s0 = sw[0];
  unsigned base = (unsigned)(b * CHW + 2 * HW + p);   // channel-2 noise index
  float x0 = init[base], x1 = init[base + HW], x2 = init[base + 2 * HW];
  const float* I2 = in2 + b * 3 * HW + p;
  float i0 = ((I2[0] * 2.0f - 1.0f) + 1.0f) * 0.5f;
  float i1 = ((I2[HW] * 2.0f - 1.0f) + 1.0f) * 0.5f;
  float i2v = ((I2[2 * HW] * 2.0f - 1.0f) + 1.0f) * 0.5f;

  unsigned ka = Kl[0], kb = Kl[1];
  for (int t = 0; t < 200; ++t) {
    unsigned kan = Kl[2 * t + 2], kbn = Kl[2 * t + 3];  // prefetch (pad-safe)
    x0 = clip1(x0 + noise_at(ka, kb, base));
    x1 = clip1(x1 + noise_at(ka, kb, base + HW));
    x2 = clip1(x2 + noise_at(ka, kb, base + 2 * HW));
    float d0 = (x0 + 1.0f) * 0.5f - i0;
    float d1 = (x1 + 1.0f) * 0.5f - i1;
    float d2 = (x2 + 1.0f) * 0.5f - i2v;
    float A = d0*d0 + d1*d1 + d2*d2;
    float sI = s0 * rsq_f(A + EPS_F);
    x0 = upd(x0, d0 * sI);
    x1 = upd(x1, d1 * sI);
    x2 = upd(x2, d2 * sI);
    ka = kan; kb = kbn;
  }
  float* outI = out + OUT_IMG_OFF + b * 3 * HW + p;
  outI[0]      = (x0 + 1.0f) * 0.5f;
  outI[HW]     = (x1 + 1.0f) * 0.5f;
  outI[2 * HW] = (x2 + 1.0f) * 0.5f;
}

__device__ __forceinline__ void block_acc2(double v0, double v1, double* a0, double* a1) {
  for (int off = 32; off > 0; off >>= 1) {
    v0 += __shfl_down(v0, off, 64);
    v1 += __shfl_down(v1, off, 64);
  }
  __shared__ double s0m[4], s1m[4];
  int lane = threadIdx.x & 63, wv = threadIdx.x >> 6;
  if (lane == 0) { s0m[wv] = v0; s1m[wv] = v1; }
  __syncthreads();
  if (threadIdx.x == 0) {
    atomicAdd(a0, s0m[0] + s0m[1] + s0m[2] + s0m[3]);
    atomicAdd(a1, s1m[0] + s1m[1] + s1m[2] + s1m[3]);
  }
}

// 96 blocks per batch, each covering 8 contiguous 256-px chunks
__global__ __launch_bounds__(256) void k_pos_energy(const float* __restrict__ t1,
    const float* __restrict__ in1, const float* __restrict__ in2,
    double* __restrict__ acc) {
  int blk = blockIdx.x;
  int b = blk / 96;
  int local = blk - b * 96;
  const float* T0 = t1 + b * 2 * HW;
  const float* T1 = T0 + HW;
  const float* I1 = in1 + b * 3 * HW;
  const float* I2 = in2 + b * 3 * HW;
  double data = 0.0, smooth = 0.0;
  for (int it = 0; it < 8; ++it) {
    int p = (local * 8 + it) * 256 + threadIdx.x;
    int h = p >> 9, w = p & 511;
    float f00 = (T0[p] / 80.0f) * 80.0f;     // mirror (t/80)*80 roundtrip
    float f10 = (T1[p] / 80.0f) * 80.0f;
    float dx0 = 0, dx1 = 0, dy0 = 0, dy1 = 0;
    if (w < 511) { dx0 = (T0[p+1]/80.0f)*80.0f - f00;  dx1 = (T1[p+1]/80.0f)*80.0f - f10; }
    if (h < 383) { dy0 = (T0[p+WW]/80.0f)*80.0f - f00; dy1 = (T1[p+WW]/80.0f)*80.0f - f10; }
    smooth += (double)sqrtf(dx0*dx0 + dx1*dx1 + dy0*dy0 + dy1*dy1 + EPS_F);
    float d0 = ((I1[p]*2.0f-1.0f)+1.0f)*0.5f        - ((I2[p]*2.0f-1.0f)+1.0f)*0.5f;
    float d1 = ((I1[p+HW]*2.0f-1.0f)+1.0f)*0.5f     - ((I2[p+HW]*2.0f-1.0f)+1.0f)*0.5f;
    float d2 = ((I1[p+2*HW]*2.0f-1.0f)+1.0f)*0.5f   - ((I2[p+2*HW]*2.0f-1.0f)+1.0f)*0.5f;
    data += (double)sqrtf(d0*d0 + d1*d1 + d2*d2 + EPS_F);
  }
  block_acc2(data, smooth, &acc[b], &acc[8 + b]);
}

__global__ __launch_bounds__(256) void k_neg_energy(const float* __restrict__ out,
    const float* __restrict__ in2, double* __restrict__ acc) {
  int blk = blockIdx.x;
  int b = blk / 96;
  int local = blk - b * 96;
  const float* F0 = out + OUT_FLOW_OFF + b * 2 * HW;   // already = 80*x
  const float* F1 = F0 + HW;
  const float* I = out + OUT_IMG_OFF + b * 3 * HW;     // already = (x+1)/2
  const float* I2 = in2 + b * 3 * HW;
  double data = 0.0, smooth = 0.0;
  for (int it = 0; it < 8; ++it) {
    int p = (local * 8 + it) * 256 + threadIdx.x;
    int h = p >> 9, w = p & 511;
    float f00 = F0[p], f10 = F1[p];
    float dx0 = 0, dx1 = 0, dy0 = 0, dy1 = 0;
    if (w < 511) { dx0 = F0[p + 1] - f00;  dx1 = F1[p + 1] - f10; }
    if (h < 383) { dy0 = F0[p + WW] - f00; dy1 = F1[p + WW] - f10; }
    smooth += (double)sqrtf(dx0*dx0 + dx1*dx1 + dy0*dy0 + dy1*dy1 + EPS_F);
    float d0 = I[p]        - ((I2[p]*2.0f-1.0f)+1.0f)*0.5f;
    float d1 = I[p+HW]     - ((I2[p+HW]*2.0f-1.0f)+1.0f)*0.5f;
    float d2 = I[p+2*HW]   - ((I2[p+2*HW]*2.0f-1.0f)+1.0f)*0.5f;
    data += (double)sqrtf(d0*d0 + d1*d1 + d2*d2 + EPS_F);
  }
  block_acc2(data, smooth, &acc[16 + b], &acc[24 + b]);
}

__global__ void k_finalize(const double* __restrict__ acc,
                           const float* __restrict__ lw, float* __restrict__ out) {
  int t = threadIdx.x;
  if (t < 16) {
    int b = t & 7, neg = t >> 3;
    double data   = acc[neg * 16 + b];
    double smooth = acc[neg * 16 + 8 + b];
    double e0 = exp((double)lw[0]), e1 = exp((double)lw[1]);
    out[t] = (float)((e0 * data + e1 * smooth) / 196608.0);
  }
}

extern "C" void kernel_launch(void* const* d_in, const int* in_sizes, int n_in,
                              void* d_out, int out_size, void* d_ws, size_t ws_size,
                              hipStream_t stream) {
  const float* t1  = (const float*)d_in[0];
  const float* in1 = (const float*)d_in[1];
  const float* in2 = (const float*)d_in[2];
  const float* init = (const float*)d_in[3];
  const float* lw  = (const float*)d_in[4];
  float* out = (float*)d_out;

  double* acc = (double*)d_ws;                          // 32 doubles
  float* sw = (float*)((char*)d_ws + 256);              // 2 floats
  float* bufFA = (float*)((char*)d_ws + 2048);          // flow ping (12.6 MB)
  size_t need = 2048 + 2 * (size_t)FLOW_N * sizeof(float);
  float* bufFB = (ws_size >= need) ? bufFA + FLOW_N
                                   : out + OUT_FLOW_OFF;  // fallback: d_out flow region

  // host-side threefry split: keys[t] = tf(0,1,0,t)  (pure integer function)
  unsigned K0[200], K1[200];
  for (int t = 0; t < 200; ++t) tf2x32(0u, 1u, 0u, (unsigned)t, K0[t], K1[t]);

  k_init<<<1, 64, 0, stream>>>(acc, sw, lw);
  k_pos_energy<<<8 * 96, 256, 0, stream>>>(t1, in1, in2, acc);

  // ---- flow trajectory: noise_0, then 199 grad(+noise) steps, then final grad.
  //      Parity: noise0 -> bufFB; t even FB->FA, t odd FA->FB; t=198 even -> FA;
  //      FINAL reads bufFA (never aliases out).
  k_fnoise0<<<FLOW_N / 256, 256, 0, stream>>>(init, bufFB, K0[0], K1[0]);
  for (int t = 0; t < 199; ++t) {
    const float* src = (t % 2 == 0) ? bufFB : bufFA;
    float* dst       = (t % 2 == 0) ? bufFA : bufFB;
    k_fstep4<false><<<NQUADS / 256, 256, 0, stream>>>(src, dst, sw,
                                                      K0[t + 1], K1[t + 1]);
  }
  k_fstep4<true><<<NQUADS / 256, 256, 0, stream>>>(bufFA, out, sw, 0u, 0u);

  // ---- img trajectory: one persistent kernel, all 200 steps in registers
  k_img<<<8 * HW / 256, 256, 0, stream>>>(init, in2, sw, out);

  k_neg_energy<<<8 * 96, 256, 0, stream>>>(out, in2, acc);
  k_finalize<<<1, 64, 0, stream>>>(acc, lw, out);
}